// Round 3
// baseline (1216.650 us; speedup 1.0000x reference)
//
#include <hip/hip_runtime.h>
#include <stdint.h>

#define NNODES 50000
#define NEDGES 1600000
#define NB     16384
#define HD     128
#define COMBW  384
#define SCAN_BLOCKS ((NNODES + 255) / 256)   // 196

typedef unsigned short u16;
typedef __bf16 bf16x8 __attribute__((ext_vector_type(8)));
typedef float  f32x4  __attribute__((ext_vector_type(4)));

__device__ __forceinline__ float b2f(u16 u){
    union { unsigned int i; float f; } v; v.i = ((unsigned int)u) << 16; return v.f;
}
__device__ __forceinline__ u16 f2b(float f){
    union { float f; unsigned int i; } v; v.f = f;
    unsigned int x = v.i;
    unsigned int r = (x + 0x7fffu + ((x >> 16) & 1u)) >> 16;
    return (u16)r;
}
// input f32 values are bf16-quantized -> truncation to high u16 is exact
__device__ __forceinline__ bf16x8 pack8(const float* __restrict__ p){
    uint4 a = *(const uint4*)p;
    uint4 b = *(const uint4*)(p + 4);
    union { u16 s[8]; bf16x8 v; } u;
    u.s[0] = (u16)(a.x >> 16); u.s[1] = (u16)(a.y >> 16);
    u.s[2] = (u16)(a.z >> 16); u.s[3] = (u16)(a.w >> 16);
    u.s[4] = (u16)(b.x >> 16); u.s[5] = (u16)(b.y >> 16);
    u.s[6] = (u16)(b.z >> 16); u.s[7] = (u16)(b.w >> 16);
    return u.v;
}

// ---------------- K0: user/item embedding gather (f32 -> f32 copy) ----------
__global__ void k_gather(const int* __restrict__ uid, const int* __restrict__ iid,
                         const float* __restrict__ utab, const float* __restrict__ itab,
                         float* __restrict__ out){
    int i = blockIdx.x * blockDim.x + threadIdx.x;   // 8 elements per thread
    const int total = 2 * NB * HD / 8;
    if (i >= total) return;
    int e8 = i * 8;
    const float* p;
    if (e8 < NB * HD) {
        int row = e8 >> 7, c = e8 & 127;
        p = utab + (size_t)uid[row] * HD + c;
    } else {
        int e2 = e8 - NB * HD;
        int row = e2 >> 7, c = e2 & 127;
        p = itab + (size_t)iid[row] * HD + c;
    }
    *(uint4*)(out + e8)     = *(const uint4*)p;
    *(uint4*)(out + e8 + 4) = *(const uint4*)(p + 4);
}

// ---------------- K1: x = relu(feat @ W^T + b), [NNODES, 32] f32 ----------------
__global__ __launch_bounds__(256) void k_feat(const float* __restrict__ feat, int K,
                                              const float* __restrict__ W,
                                              const float* __restrict__ bias,
                                              float* __restrict__ xout){
    int wave = threadIdx.x >> 6, lane = threadIdx.x & 63;
    int quad = lane >> 4, m = lane & 15;
    int row0 = blockIdx.x * 64 + wave * 16;
    int arow = row0 + m; if (arow >= NNODES) arow = NNODES - 1;
    const float* ap  = feat + (size_t)arow * K + quad * 8;
    const float* bp0 = W + (size_t)m        * K + quad * 8;
    const float* bp1 = W + (size_t)(m + 16) * K + quad * 8;
    f32x4 c0 = {0.f,0.f,0.f,0.f}, c1 = {0.f,0.f,0.f,0.f};
    for (int k = 0; k < K; k += 32){
        bf16x8 a  = pack8(ap  + k);
        bf16x8 b0 = pack8(bp0 + k);
        bf16x8 b1 = pack8(bp1 + k);
        c0 = __builtin_amdgcn_mfma_f32_16x16x32_bf16(a, b0, c0, 0, 0, 0);
        c1 = __builtin_amdgcn_mfma_f32_16x16x32_bf16(a, b1, c1, 0, 0, 0);
    }
    float bv0 = bias[m], bv1 = bias[m + 16];
    #pragma unroll
    for (int i = 0; i < 4; i++){
        int r = row0 + quad * 4 + i;
        if (r < NNODES){
            float v0 = c0[i] + bv0; v0 = v0 > 0.f ? v0 : 0.f;
            float v1 = c1[i] + bv1; v1 = v1 > 0.f ? v1 : 0.f;
            xout[(size_t)r * 32 + m]      = v0;
            xout[(size_t)r * 32 + m + 16] = v1;
        }
    }
}

// ---------------- K2: h = x @ gW^T, el/er — scalar-broadcast GEMM ----------------
__global__ __launch_bounds__(256) void k_node(const float* __restrict__ x,
                                              const float* __restrict__ gW,
                                              const float* __restrict__ al,
                                              const float* __restrict__ ar,
                                              u16* __restrict__ hout,   // hcat + mod*128, row stride 384
                                              float* __restrict__ el,
                                              float* __restrict__ er){
    int head = blockIdx.y;
    int n = blockIdx.x * blockDim.x + threadIdx.x;
    int nc = n < NNODES ? n : NNODES - 1;   // tail threads duplicate last node (benign)
    float xr[32];
    const float4* xp = (const float4*)(x + (size_t)nc * 32);
    #pragma unroll
    for (int i = 0; i < 8; i++){
        float4 v = xp[i];
        xr[4*i] = v.x; xr[4*i+1] = v.y; xr[4*i+2] = v.z; xr[4*i+3] = v.w;
    }
    const float* wbase = gW + head * 1024;   // rows head*32 .. head*32+31
    const float* alh = al + head * 32;
    const float* arh = ar + head * 32;
    u16* hp = hout + (size_t)nc * COMBW + head * 32;
    float elv = 0.f, erv = 0.f;
    #pragma unroll
    for (int cg = 0; cg < 4; cg++){
        float acc[8];
        #pragma unroll
        for (int c = 0; c < 8; c++){
            const float* wr = wbase + (cg * 8 + c) * 32;
            float a = 0.f;
            #pragma unroll
            for (int k = 0; k < 32; k++) a += xr[k] * wr[k];
            acc[c] = a;
            elv += a * alh[cg * 8 + c];
            erv += a * arh[cg * 8 + c];
        }
        union { u16 s[8]; uint4 q; } u;
        #pragma unroll
        for (int c = 0; c < 8; c++) u.s[c] = f2b(acc[c]);
        *(uint4*)(hp + cg * 8) = u.q;
    }
    el[(size_t)nc * 4 + head] = elv;
    er[(size_t)nc * 4 + head] = erv;
}

// ---------------- K3: CSR build ----------------
__global__ void k_hist(const int* __restrict__ dst, int* __restrict__ cnt){
    int i = blockIdx.x * blockDim.x + threadIdx.x;
    if (i < NEDGES) atomicAdd(&cnt[dst[i]], 1);
}

// Multi-block exclusive scan: scan1 (block-local) -> scan2 (block sums) -> scan3 (add offsets)
__global__ __launch_bounds__(256) void k_scan1(const int* __restrict__ cnt,
                                               int* __restrict__ rp,
                                               int* __restrict__ bsum){
    __shared__ int ws[4];
    int t = threadIdx.x, lane = t & 63, w = t >> 6;
    int i = blockIdx.x * 256 + t;
    int v = (i < NNODES) ? cnt[i] : 0;
    int x = v;
    #pragma unroll
    for (int off = 1; off < 64; off <<= 1){
        int u = __shfl_up(x, off, 64);
        if (lane >= off) x += u;
    }
    if (lane == 63) ws[w] = x;
    __syncthreads();
    if (t == 0){
        int s = 0;
        #pragma unroll
        for (int j = 0; j < 4; j++){ int tmp = ws[j]; ws[j] = s; s += tmp; }
        bsum[blockIdx.x] = s;
    }
    __syncthreads();
    if (i < NNODES) rp[i] = ws[w] + x - v;   // exclusive, block-local
}

__global__ __launch_bounds__(256) void k_scan2(int* __restrict__ bsum, int* __restrict__ rp){
    __shared__ int ws[4];
    int t = threadIdx.x, lane = t & 63, w = t >> 6;
    int v = (t < SCAN_BLOCKS) ? bsum[t] : 0;
    int x = v;
    #pragma unroll
    for (int off = 1; off < 64; off <<= 1){
        int u = __shfl_up(x, off, 64);
        if (lane >= off) x += u;
    }
    if (lane == 63) ws[w] = x;
    __syncthreads();
    if (t == 0){
        int s = 0;
        #pragma unroll
        for (int j = 0; j < 4; j++){ int tmp = ws[j]; ws[j] = s; s += tmp; }
        rp[NNODES] = s;   // total = NEDGES
    }
    __syncthreads();
    if (t < SCAN_BLOCKS) bsum[t] = ws[w] + x - v;   // exclusive block offsets
}

__global__ __launch_bounds__(256) void k_scan3(int* __restrict__ rp, const int* __restrict__ bsum){
    int i = blockIdx.x * 256 + threadIdx.x;
    if (i < NNODES) rp[i] += bsum[blockIdx.x];
}

// ---------------- K3b: CSR scatter fused with per-edge attention weights
// written in CSR position order (weight for slot p comes from edge i at p).
template<int WITHW>
__global__ __launch_bounds__(256) void k_scatter(const int* __restrict__ src, const int* __restrict__ dst,
                          const int* __restrict__ rp, int* __restrict__ fill,
                          int* __restrict__ col,
                          const float* __restrict__ el0, const float* __restrict__ er0,
                          const float* __restrict__ el1, const float* __restrict__ er1,
                          const float* __restrict__ el2, const float* __restrict__ er2,
                          float* __restrict__ w){
    int i = blockIdx.x * blockDim.x + threadIdx.x;
    if (i >= NEDGES) return;
    int s = src[i], d = dst[i];
    int p = rp[d] + atomicAdd(&fill[d], 1);
    col[p] = s;
    if (WITHW){
        float4 l0 = *(const float4*)(el0 + (size_t)s * 4);
        float4 r0 = *(const float4*)(er0 + (size_t)d * 4);
        float4 l1 = *(const float4*)(el1 + (size_t)s * 4);
        float4 r1 = *(const float4*)(er1 + (size_t)d * 4);
        float4 l2 = *(const float4*)(el2 + (size_t)s * 4);
        float4 r2 = *(const float4*)(er2 + (size_t)d * 4);
        float4 w0, w1, w2;
        #define LKEXP(a, b) __expf(fmaxf((a) + (b), 0.2f * ((a) + (b))))
        w0.x = LKEXP(l0.x, r0.x); w0.y = LKEXP(l0.y, r0.y); w0.z = LKEXP(l0.z, r0.z); w0.w = LKEXP(l0.w, r0.w);
        w1.x = LKEXP(l1.x, r1.x); w1.y = LKEXP(l1.y, r1.y); w1.z = LKEXP(l1.z, r1.z); w1.w = LKEXP(l1.w, r1.w);
        w2.x = LKEXP(l2.x, r2.x); w2.y = LKEXP(l2.y, r2.y); w2.z = LKEXP(l2.z, r2.z); w2.w = LKEXP(l2.w, r2.w);
        #undef LKEXP
        float4* wp = (float4*)(w + (size_t)p * 12);
        wp[0] = w0; wp[1] = w1; wp[2] = w2;
    }
}

// ---------------- K4: fused 3-modality GAT aggregation, 384 threads ----------
// Thread t owns one output element: mod = t>>7, head = (t>>5)&3, col = t&127.
// Per edge: 1 broadcast w load + 1 contiguous 128B/wave h load. Unroll x4 for MLP.
// Accumulation order per thread is strictly increasing e -> bitwise == round 2.
__global__ __launch_bounds__(384) void k_gat(
        const int* __restrict__ rp, const int* __restrict__ col,
        const u16* __restrict__ hcat, const float* __restrict__ w,
        const float* __restrict__ gb0, const float* __restrict__ gb1, const float* __restrict__ gb2,
        u16* __restrict__ comb){
    int n = blockIdx.x, t = threadIdx.x;
    int mod = t >> 7;
    int head = (t >> 5) & 3;
    int beg = rp[n], end = rp[n + 1];
    float acc = 0.f, dsum = 0.f;
    const float* wp = w + (size_t)beg * 12 + mod * 4 + head;
    const u16* hbase = hcat + t;
    int e = beg;
    for (; e + 4 <= end; e += 4){
        int s0 = col[e], s1 = col[e + 1], s2 = col[e + 2], s3 = col[e + 3];
        float w0 = wp[0], w1 = wp[12], w2 = wp[24], w3 = wp[36];
        wp += 48;
        float h0 = b2f(hbase[(size_t)s0 * COMBW]);
        float h1 = b2f(hbase[(size_t)s1 * COMBW]);
        float h2 = b2f(hbase[(size_t)s2 * COMBW]);
        float h3 = b2f(hbase[(size_t)s3 * COMBW]);
        acc += w0 * h0; dsum += w0;
        acc += w1 * h1; dsum += w1;
        acc += w2 * h2; dsum += w2;
        acc += w3 * h3; dsum += w3;
    }
    for (; e < end; e++, wp += 12){
        int s = col[e];
        float wv = wp[0];
        acc += wv * b2f(hbase[(size_t)s * COMBW]);
        dsum += wv;
    }
    const float* gb = (mod == 0) ? gb0 : ((mod == 1) ? gb1 : gb2);
    comb[(size_t)n * COMBW + t] = f2b(acc / fmaxf(dsum, 1e-9f) + gb[t & 127]);
}

// Fallback (no w buffer): round-2 inline path, 128 threads.
__global__ __launch_bounds__(128) void k_gat_fb(
        const int* __restrict__ rp, const int* __restrict__ col,
        const u16* __restrict__ hcat,
        const float* __restrict__ el0, const float* __restrict__ er0,
        const float* __restrict__ el1, const float* __restrict__ er1,
        const float* __restrict__ el2, const float* __restrict__ er2,
        const float* __restrict__ gb0, const float* __restrict__ gb1, const float* __restrict__ gb2,
        u16* __restrict__ comb){
    int n = blockIdx.x, t = threadIdx.x;
    int head = t >> 5;
    float a0 = 0.f, a1 = 0.f, a2 = 0.f, d0 = 0.f, d1 = 0.f, d2 = 0.f;
    int beg = rp[n], end = rp[n + 1];
    float e0 = er0[(size_t)n * 4 + head];
    float e1 = er1[(size_t)n * 4 + head];
    float e2 = er2[(size_t)n * 4 + head];
    for (int e = beg; e < end; e++){
        int s = col[e];
        const u16* hp = hcat + (size_t)s * COMBW + t;
        float v0 = el0[(size_t)s * 4 + head] + e0; v0 = fmaxf(v0, 0.2f * v0);
        float v1 = el1[(size_t)s * 4 + head] + e1; v1 = fmaxf(v1, 0.2f * v1);
        float v2 = el2[(size_t)s * 4 + head] + e2; v2 = fmaxf(v2, 0.2f * v2);
        float w0 = __expf(v0), w1 = __expf(v1), w2 = __expf(v2);
        a0 += w0 * b2f(hp[0]);   d0 += w0;
        a1 += w1 * b2f(hp[128]); d1 += w1;
        a2 += w2 * b2f(hp[256]); d2 += w2;
    }
    size_t o = (size_t)n * COMBW;
    comb[o + t]       = f2b(a0 / fmaxf(d0, 1e-9f) + gb0[t]);
    comb[o + 128 + t] = f2b(a1 / fmaxf(d1, 1e-9f) + gb1[t]);
    comb[o + 256 + t] = f2b(a2 / fmaxf(d2, 1e-9f) + gb2[t]);
}

// ---------------- K5: out = relu(comb @ fcW^T + fcb), f32 out ----------------
__global__ __launch_bounds__(256) void k_fc(const u16* __restrict__ comb,
                                            const float* __restrict__ fcW,
                                            const float* __restrict__ fcb,
                                            float* __restrict__ out){
    int wave = threadIdx.x >> 6, lane = threadIdx.x & 63;
    int quad = lane >> 4, m = lane & 15;
    int row0 = blockIdx.x * 64 + wave * 16;
    int arow = row0 + m; if (arow >= NNODES) arow = NNODES - 1;
    const u16* ap = comb + (size_t)arow * COMBW + quad * 8;
    f32x4 c[8];
    #pragma unroll
    for (int f = 0; f < 8; f++) c[f] = (f32x4){0.f,0.f,0.f,0.f};
    for (int k = 0; k < COMBW; k += 32){
        bf16x8 a = *(const bf16x8*)(ap + k);
        #pragma unroll
        for (int f = 0; f < 8; f++){
            bf16x8 b = pack8(fcW + (size_t)(f * 16 + m) * COMBW + k + quad * 8);
            c[f] = __builtin_amdgcn_mfma_f32_16x16x32_bf16(a, b, c[f], 0, 0, 0);
        }
    }
    #pragma unroll
    for (int f = 0; f < 8; f++){
        int colc = f * 16 + m;
        float bv = fcb[colc];
        #pragma unroll
        for (int i = 0; i < 4; i++){
            int r = row0 + quad * 4 + i;
            if (r < NNODES){
                float v = c[f][i] + bv; v = v > 0.f ? v : 0.f;
                out[(size_t)(2 * NB * HD) + (size_t)r * HD + colc] = v;
            }
        }
    }
}

extern "C" void kernel_launch(void* const* d_in, const int* in_sizes, int n_in,
                              void* d_out, int out_size, void* d_ws, size_t ws_size,
                              hipStream_t stream){
    const int* uid = (const int*)d_in[0];
    const int* iid = (const int*)d_in[1];
    const int* src = (const int*)d_in[2];
    const int* dst = (const int*)d_in[3];
    const float* fimg = (const float*)d_in[4];
    const float* ftxt = (const float*)d_in[5];
    const float* faud = (const float*)d_in[6];
    const float* utab = (const float*)d_in[7];
    const float* itab = (const float*)d_in[8];
    const float* Wi = (const float*)d_in[9],  *bi = (const float*)d_in[10];
    const float* Wt = (const float*)d_in[11], *bt = (const float*)d_in[12];
    const float* Wa = (const float*)d_in[13], *ba = (const float*)d_in[14];
    const float* gWi = (const float*)d_in[15], *ali = (const float*)d_in[16],
               *ari = (const float*)d_in[17], *gbi = (const float*)d_in[18];
    const float* gWt = (const float*)d_in[19], *alt = (const float*)d_in[20],
               *art = (const float*)d_in[21], *gbt = (const float*)d_in[22];
    const float* gWa = (const float*)d_in[23], *ala = (const float*)d_in[24],
               *ara = (const float*)d_in[25], *gba = (const float*)d_in[26];
    const float* fcW = (const float*)d_in[27], *fcb = (const float*)d_in[28];
    float* out = (float*)d_out;

    char* ws = (char*)d_ws;
    u16*   hcat = (u16*)  (ws + 0);           // 38.4 MB  [n][3][128] interleaved
    u16*   comb = (u16*)  (ws + 38400000);    // 38.4 MB
    float* x    = (float*)(ws + 76800000);    // 6.4 MB (reused per modality)
    float* el   = (float*)(ws + 83200000);    // 3 x 800000 B
    float* er   = (float*)(ws + 85600000);    // 3 x 800000 B
    int*   cnt  = (int*)  (ws + 88000000);    // 200 KB
    int*   fill = (int*)  (ws + 88200000);    // 200 KB
    int*   rp   = (int*)  (ws + 88400000);    // 200 KB (+pad)
    int*   col  = (int*)  (ws + 88600064);    // 6.4 MB
    float* w    = (float*)(ws + 95000064);    // 76.8 MB (edge weights, CSR order, optional)
    const size_t NEED_W = 95000064u + (size_t)NEDGES * 12 * sizeof(float);
    int*   bsum = (int*)x;                    // overlay: x is first written AFTER scan3 (stream order)

    float* el0 = el,           *el1 = el + 200000, *el2 = el + 400000;
    float* er0 = er,           *er1 = er + 200000, *er2 = er + 400000;

    hipMemsetAsync(cnt, 0, 400000, stream);   // cnt + fill (adjacent)

    // CSR histogram + multi-block scan (scatter deferred until el/er ready)
    k_hist<<<(NEDGES + 255) / 256, 256, 0, stream>>>(dst, cnt);
    k_scan1<<<SCAN_BLOCKS, 256, 0, stream>>>(cnt, rp, bsum);
    k_scan2<<<1, 256, 0, stream>>>(bsum, rp);
    k_scan3<<<SCAN_BLOCKS, 256, 0, stream>>>(rp, bsum);

    // Embedding gathers straight to d_out
    k_gather<<<(2 * NB * HD / 8 + 255) / 256, 256, 0, stream>>>(uid, iid, utab, itab, out);

    // Modality pipelines (x buffer reused; stream-ordered)
    dim3 ngrid((NNODES + 255) / 256, 4);
    k_feat<<<(NNODES + 63) / 64, 256, 0, stream>>>(fimg, 1024, Wi, bi, x);
    k_node<<<ngrid, 256, 0, stream>>>(x, gWi, ali, ari, hcat,       el0, er0);
    k_feat<<<(NNODES + 63) / 64, 256, 0, stream>>>(ftxt, 768, Wt, bt, x);
    k_node<<<ngrid, 256, 0, stream>>>(x, gWt, alt, art, hcat + 128, el1, er1);
    k_feat<<<(NNODES + 63) / 64, 256, 0, stream>>>(faud, 128, Wa, ba, x);
    k_node<<<ngrid, 256, 0, stream>>>(x, gWa, ala, ara, hcat + 256, el2, er2);

    // Fused edge-softmax + aggregation for all 3 modalities
    if (ws_size >= NEED_W){
        k_scatter<1><<<(NEDGES + 255) / 256, 256, 0, stream>>>(src, dst, rp, fill, col,
                                                               el0, er0, el1, er1, el2, er2, w);
        k_gat<<<NNODES, 384, 0, stream>>>(rp, col, hcat, w, gbi, gbt, gba, comb);
    } else {
        k_scatter<0><<<(NEDGES + 255) / 256, 256, 0, stream>>>(src, dst, rp, fill, col,
                                                               el0, er0, el1, er1, el2, er2, w);
        k_gat_fb<<<NNODES, 128, 0, stream>>>(rp, col, hcat,
                                             el0, er0, el1, er1, el2, er2,
                                             gbi, gbt, gba, comb);
    }

    // Final fc
    k_fc<<<(NNODES + 63) / 64, 256, 0, stream>>>(comb, fcW, fcb, out);
}

// Round 4
// 1066.041 us; speedup vs baseline: 1.1413x; 1.1413x over previous
//
#include <hip/hip_runtime.h>
#include <stdint.h>

#define NNODES 50000
#define NEDGES 1600000
#define NB     16384
#define HD     128
#define COMBW  384
#define SCAN_BLOCKS ((NNODES + 255) / 256)   // 196

typedef unsigned short u16;
typedef __bf16 bf16x8 __attribute__((ext_vector_type(8)));
typedef float  f32x4  __attribute__((ext_vector_type(4)));

__device__ __forceinline__ float b2f(u16 u){
    union { unsigned int i; float f; } v; v.i = ((unsigned int)u) << 16; return v.f;
}
__device__ __forceinline__ u16 f2b(float f){
    union { float f; unsigned int i; } v; v.f = f;
    unsigned int x = v.i;
    unsigned int r = (x + 0x7fffu + ((x >> 16) & 1u)) >> 16;
    return (u16)r;
}
// input f32 values are bf16-quantized -> truncation to high u16 is exact
__device__ __forceinline__ bf16x8 pack8(const float* __restrict__ p){
    uint4 a = *(const uint4*)p;
    uint4 b = *(const uint4*)(p + 4);
    union { u16 s[8]; bf16x8 v; } u;
    u.s[0] = (u16)(a.x >> 16); u.s[1] = (u16)(a.y >> 16);
    u.s[2] = (u16)(a.z >> 16); u.s[3] = (u16)(a.w >> 16);
    u.s[4] = (u16)(b.x >> 16); u.s[5] = (u16)(b.y >> 16);
    u.s[6] = (u16)(b.z >> 16); u.s[7] = (u16)(b.w >> 16);
    return u.v;
}

// ---------------- K0: user/item embedding gather (f32 -> f32 copy) ----------
__global__ void k_gather(const int* __restrict__ uid, const int* __restrict__ iid,
                         const float* __restrict__ utab, const float* __restrict__ itab,
                         float* __restrict__ out){
    int i = blockIdx.x * blockDim.x + threadIdx.x;   // 8 elements per thread
    const int total = 2 * NB * HD / 8;
    if (i >= total) return;
    int e8 = i * 8;
    const float* p;
    if (e8 < NB * HD) {
        int row = e8 >> 7, c = e8 & 127;
        p = utab + (size_t)uid[row] * HD + c;
    } else {
        int e2 = e8 - NB * HD;
        int row = e2 >> 7, c = e2 & 127;
        p = itab + (size_t)iid[row] * HD + c;
    }
    *(uint4*)(out + e8)     = *(const uint4*)p;
    *(uint4*)(out + e8 + 4) = *(const uint4*)(p + 4);
}

// ---------------- Kp: weight pre-pack (f32 -> bf16, truncation == pack8 bits) ---
__global__ __launch_bounds__(256) void k_pack(const float* __restrict__ s,
                                              u16* __restrict__ d, int n8){
    int i = blockIdx.x * 256 + threadIdx.x;
    if (i >= n8) return;
    const float* p = s + (size_t)i * 8;
    uint4 a = *(const uint4*)p, b = *(const uint4*)(p + 4);
    union { u16 v[8]; uint4 q; } u;
    u.v[0] = (u16)(a.x >> 16); u.v[1] = (u16)(a.y >> 16);
    u.v[2] = (u16)(a.z >> 16); u.v[3] = (u16)(a.w >> 16);
    u.v[4] = (u16)(b.x >> 16); u.v[5] = (u16)(b.y >> 16);
    u.v[6] = (u16)(b.z >> 16); u.v[7] = (u16)(b.w >> 16);
    *(uint4*)(d + (size_t)i * 8) = u.q;
}

// Packs Wi (32x1024) | Wt (32x768) | Wa (32x128) into one contiguous bf16 buffer.
__global__ __launch_bounds__(256) void k_pack3(const float* __restrict__ Wi,
                                               const float* __restrict__ Wt,
                                               const float* __restrict__ Wa,
                                               u16* __restrict__ d){
    int i = blockIdx.x * 256 + threadIdx.x;   // 0..7679 (61440 elems / 8)
    if (i >= 7680) return;
    const float* p;
    if (i < 4096)       p = Wi + (size_t)i * 8;
    else if (i < 7168)  p = Wt + (size_t)(i - 4096) * 8;
    else                p = Wa + (size_t)(i - 7168) * 8;
    uint4 a = *(const uint4*)p, b = *(const uint4*)(p + 4);
    union { u16 v[8]; uint4 q; } u;
    u.v[0] = (u16)(a.x >> 16); u.v[1] = (u16)(a.y >> 16);
    u.v[2] = (u16)(a.z >> 16); u.v[3] = (u16)(a.w >> 16);
    u.v[4] = (u16)(b.x >> 16); u.v[5] = (u16)(b.y >> 16);
    u.v[6] = (u16)(b.z >> 16); u.v[7] = (u16)(b.w >> 16);
    *(uint4*)(d + (size_t)i * 8) = u.q;
}

// ---------------- K1: x = relu(feat @ W^T + b), [NNODES, 32] f32 ----------------
// B operand pre-packed to bf16 (direct 16B loads, no per-block repack).
__global__ __launch_bounds__(256) void k_feat(const float* __restrict__ feat, int K,
                                              const u16* __restrict__ pW,
                                              const float* __restrict__ bias,
                                              float* __restrict__ xout){
    int wave = threadIdx.x >> 6, lane = threadIdx.x & 63;
    int quad = lane >> 4, m = lane & 15;
    int row0 = blockIdx.x * 64 + wave * 16;
    int arow = row0 + m; if (arow >= NNODES) arow = NNODES - 1;
    const float* ap = feat + (size_t)arow * K + quad * 8;
    const u16* bp0 = pW + (size_t)m        * K + quad * 8;
    const u16* bp1 = pW + (size_t)(m + 16) * K + quad * 8;
    f32x4 c0 = {0.f,0.f,0.f,0.f}, c1 = {0.f,0.f,0.f,0.f};
    for (int k = 0; k < K; k += 32){
        bf16x8 a  = pack8(ap + k);
        bf16x8 b0 = *(const bf16x8*)(bp0 + k);
        bf16x8 b1 = *(const bf16x8*)(bp1 + k);
        c0 = __builtin_amdgcn_mfma_f32_16x16x32_bf16(a, b0, c0, 0, 0, 0);
        c1 = __builtin_amdgcn_mfma_f32_16x16x32_bf16(a, b1, c1, 0, 0, 0);
    }
    float bv0 = bias[m], bv1 = bias[m + 16];
    #pragma unroll
    for (int i = 0; i < 4; i++){
        int r = row0 + quad * 4 + i;
        if (r < NNODES){
            float v0 = c0[i] + bv0; v0 = v0 > 0.f ? v0 : 0.f;
            float v1 = c1[i] + bv1; v1 = v1 > 0.f ? v1 : 0.f;
            xout[(size_t)r * 32 + m]      = v0;
            xout[(size_t)r * 32 + m + 16] = v1;
        }
    }
}

// ---------------- K2: h = x @ gW^T, el/er — scalar-broadcast GEMM ----------------
__global__ __launch_bounds__(256) void k_node(const float* __restrict__ x,
                                              const float* __restrict__ gW,
                                              const float* __restrict__ al,
                                              const float* __restrict__ ar,
                                              u16* __restrict__ hout,   // hcat + mod*128, row stride 384
                                              float* __restrict__ el,
                                              float* __restrict__ er){
    int head = blockIdx.y;
    int n = blockIdx.x * blockDim.x + threadIdx.x;
    int nc = n < NNODES ? n : NNODES - 1;   // tail threads duplicate last node (benign)
    float xr[32];
    const float4* xp = (const float4*)(x + (size_t)nc * 32);
    #pragma unroll
    for (int i = 0; i < 8; i++){
        float4 v = xp[i];
        xr[4*i] = v.x; xr[4*i+1] = v.y; xr[4*i+2] = v.z; xr[4*i+3] = v.w;
    }
    const float* wbase = gW + head * 1024;   // rows head*32 .. head*32+31
    const float* alh = al + head * 32;
    const float* arh = ar + head * 32;
    u16* hp = hout + (size_t)nc * COMBW + head * 32;
    float elv = 0.f, erv = 0.f;
    #pragma unroll
    for (int cg = 0; cg < 4; cg++){
        float acc[8];
        #pragma unroll
        for (int c = 0; c < 8; c++){
            const float* wr = wbase + (cg * 8 + c) * 32;
            float a = 0.f;
            #pragma unroll
            for (int k = 0; k < 32; k++) a += xr[k] * wr[k];
            acc[c] = a;
            elv += a * alh[cg * 8 + c];
            erv += a * arh[cg * 8 + c];
        }
        union { u16 s[8]; uint4 q; } u;
        #pragma unroll
        for (int c = 0; c < 8; c++) u.s[c] = f2b(acc[c]);
        *(uint4*)(hp + cg * 8) = u.q;
    }
    el[(size_t)nc * 4 + head] = elv;
    er[(size_t)nc * 4 + head] = erv;
}

// ---------------- K3: CSR build ----------------
__global__ void k_hist(const int* __restrict__ dst, int* __restrict__ cnt){
    int i = blockIdx.x * blockDim.x + threadIdx.x;
    if (i < NEDGES) atomicAdd(&cnt[dst[i]], 1);
}

// Multi-block exclusive scan: scan1 (block-local) -> scan2 (block sums) -> scan3 (add offsets)
__global__ __launch_bounds__(256) void k_scan1(const int* __restrict__ cnt,
                                               int* __restrict__ rp,
                                               int* __restrict__ bsum){
    __shared__ int ws[4];
    int t = threadIdx.x, lane = t & 63, w = t >> 6;
    int i = blockIdx.x * 256 + t;
    int v = (i < NNODES) ? cnt[i] : 0;
    int x = v;
    #pragma unroll
    for (int off = 1; off < 64; off <<= 1){
        int u = __shfl_up(x, off, 64);
        if (lane >= off) x += u;
    }
    if (lane == 63) ws[w] = x;
    __syncthreads();
    if (t == 0){
        int s = 0;
        #pragma unroll
        for (int j = 0; j < 4; j++){ int tmp = ws[j]; ws[j] = s; s += tmp; }
        bsum[blockIdx.x] = s;
    }
    __syncthreads();
    if (i < NNODES) rp[i] = ws[w] + x - v;   // exclusive, block-local
}

__global__ __launch_bounds__(256) void k_scan2(int* __restrict__ bsum, int* __restrict__ rp){
    __shared__ int ws[4];
    int t = threadIdx.x, lane = t & 63, w = t >> 6;
    int v = (t < SCAN_BLOCKS) ? bsum[t] : 0;
    int x = v;
    #pragma unroll
    for (int off = 1; off < 64; off <<= 1){
        int u = __shfl_up(x, off, 64);
        if (lane >= off) x += u;
    }
    if (lane == 63) ws[w] = x;
    __syncthreads();
    if (t == 0){
        int s = 0;
        #pragma unroll
        for (int j = 0; j < 4; j++){ int tmp = ws[j]; ws[j] = s; s += tmp; }
        rp[NNODES] = s;   // total = NEDGES
    }
    __syncthreads();
    if (t < SCAN_BLOCKS) bsum[t] = ws[w] + x - v;   // exclusive block offsets
}

__global__ __launch_bounds__(256) void k_scan3(int* __restrict__ rp, const int* __restrict__ bsum){
    int i = blockIdx.x * 256 + threadIdx.x;
    if (i < NNODES) rp[i] += bsum[blockIdx.x];
}

// ---------------- K3b: CSR scatter fused with per-edge attention weights
// written in CSR position order (weight for slot p comes from edge i at p).
template<int WITHW>
__global__ __launch_bounds__(256) void k_scatter(const int* __restrict__ src, const int* __restrict__ dst,
                          const int* __restrict__ rp, int* __restrict__ fill,
                          int* __restrict__ col,
                          const float* __restrict__ el0, const float* __restrict__ er0,
                          const float* __restrict__ el1, const float* __restrict__ er1,
                          const float* __restrict__ el2, const float* __restrict__ er2,
                          float* __restrict__ w){
    int i = blockIdx.x * blockDim.x + threadIdx.x;
    if (i >= NEDGES) return;
    int s = src[i], d = dst[i];
    int p = rp[d] + atomicAdd(&fill[d], 1);
    col[p] = s;
    if (WITHW){
        float4 l0 = *(const float4*)(el0 + (size_t)s * 4);
        float4 r0 = *(const float4*)(er0 + (size_t)d * 4);
        float4 l1 = *(const float4*)(el1 + (size_t)s * 4);
        float4 r1 = *(const float4*)(er1 + (size_t)d * 4);
        float4 l2 = *(const float4*)(el2 + (size_t)s * 4);
        float4 r2 = *(const float4*)(er2 + (size_t)d * 4);
        float4 w0, w1, w2;
        #define LKEXP(a, b) __expf(fmaxf((a) + (b), 0.2f * ((a) + (b))))
        w0.x = LKEXP(l0.x, r0.x); w0.y = LKEXP(l0.y, r0.y); w0.z = LKEXP(l0.z, r0.z); w0.w = LKEXP(l0.w, r0.w);
        w1.x = LKEXP(l1.x, r1.x); w1.y = LKEXP(l1.y, r1.y); w1.z = LKEXP(l1.z, r1.z); w1.w = LKEXP(l1.w, r1.w);
        w2.x = LKEXP(l2.x, r2.x); w2.y = LKEXP(l2.y, r2.y); w2.z = LKEXP(l2.z, r2.z); w2.w = LKEXP(l2.w, r2.w);
        #undef LKEXP
        float4* wp = (float4*)(w + (size_t)p * 12);
        wp[0] = w0; wp[1] = w1; wp[2] = w2;
    }
}

// ---------------- K4: fused 3-modality GAT aggregation, 128 threads ----------
// Round-2 shape (2 waves/block, 84% occupancy) + 4-edge unroll: 12 independent
// h-gathers in flight per thread. Per-accumulator add order is strictly
// increasing e -> bitwise-identical to round 2.
__global__ __launch_bounds__(128) void k_gat(
        const int* __restrict__ rp, const int* __restrict__ col,
        const u16* __restrict__ hcat, const float* __restrict__ w,
        const float* __restrict__ gb0, const float* __restrict__ gb1, const float* __restrict__ gb2,
        u16* __restrict__ comb){
    int n = blockIdx.x, t = threadIdx.x;
    int beg = rp[n], end = rp[n + 1];
    float a0 = 0.f, a1 = 0.f, a2 = 0.f, d0 = 0.f, d1 = 0.f, d2 = 0.f;
    const float* wp = w + (size_t)beg * 12 + (t >> 5);   // + head
    int e = beg;
    for (; e + 4 <= end; e += 4, wp += 48){
        int s0 = col[e], s1 = col[e + 1], s2 = col[e + 2], s3 = col[e + 3];
        const u16* p0 = hcat + (size_t)s0 * COMBW + t;
        const u16* p1 = hcat + (size_t)s1 * COMBW + t;
        const u16* p2 = hcat + (size_t)s2 * COMBW + t;
        const u16* p3 = hcat + (size_t)s3 * COMBW + t;
        float w00 = wp[0],  w01 = wp[4],  w02 = wp[8];
        float w10 = wp[12], w11 = wp[16], w12 = wp[20];
        float w20 = wp[24], w21 = wp[28], w22 = wp[32];
        float w30 = wp[36], w31 = wp[40], w32 = wp[44];
        float h00 = b2f(p0[0]), h01 = b2f(p0[128]), h02 = b2f(p0[256]);
        float h10 = b2f(p1[0]), h11 = b2f(p1[128]), h12 = b2f(p1[256]);
        float h20 = b2f(p2[0]), h21 = b2f(p2[128]), h22 = b2f(p2[256]);
        float h30 = b2f(p3[0]), h31 = b2f(p3[128]), h32 = b2f(p3[256]);
        a0 += w00 * h00; d0 += w00; a1 += w01 * h01; d1 += w01; a2 += w02 * h02; d2 += w02;
        a0 += w10 * h10; d0 += w10; a1 += w11 * h11; d1 += w11; a2 += w12 * h12; d2 += w12;
        a0 += w20 * h20; d0 += w20; a1 += w21 * h21; d1 += w21; a2 += w22 * h22; d2 += w22;
        a0 += w30 * h30; d0 += w30; a1 += w31 * h31; d1 += w31; a2 += w32 * h32; d2 += w32;
    }
    for (; e < end; e++, wp += 12){
        int s = col[e];
        const u16* hp = hcat + (size_t)s * COMBW + t;
        float w0 = wp[0], w1 = wp[4], w2 = wp[8];
        a0 += w0 * b2f(hp[0]);   d0 += w0;
        a1 += w1 * b2f(hp[128]); d1 += w1;
        a2 += w2 * b2f(hp[256]); d2 += w2;
    }
    size_t o = (size_t)n * COMBW;
    comb[o + t]       = f2b(a0 / fmaxf(d0, 1e-9f) + gb0[t]);
    comb[o + 128 + t] = f2b(a1 / fmaxf(d1, 1e-9f) + gb1[t]);
    comb[o + 256 + t] = f2b(a2 / fmaxf(d2, 1e-9f) + gb2[t]);
}

// Fallback (no w buffer): round-2 inline path, 128 threads.
__global__ __launch_bounds__(128) void k_gat_fb(
        const int* __restrict__ rp, const int* __restrict__ col,
        const u16* __restrict__ hcat,
        const float* __restrict__ el0, const float* __restrict__ er0,
        const float* __restrict__ el1, const float* __restrict__ er1,
        const float* __restrict__ el2, const float* __restrict__ er2,
        const float* __restrict__ gb0, const float* __restrict__ gb1, const float* __restrict__ gb2,
        u16* __restrict__ comb){
    int n = blockIdx.x, t = threadIdx.x;
    int head = t >> 5;
    float a0 = 0.f, a1 = 0.f, a2 = 0.f, d0 = 0.f, d1 = 0.f, d2 = 0.f;
    int beg = rp[n], end = rp[n + 1];
    float e0 = er0[(size_t)n * 4 + head];
    float e1 = er1[(size_t)n * 4 + head];
    float e2 = er2[(size_t)n * 4 + head];
    for (int e = beg; e < end; e++){
        int s = col[e];
        const u16* hp = hcat + (size_t)s * COMBW + t;
        float v0 = el0[(size_t)s * 4 + head] + e0; v0 = fmaxf(v0, 0.2f * v0);
        float v1 = el1[(size_t)s * 4 + head] + e1; v1 = fmaxf(v1, 0.2f * v1);
        float v2 = el2[(size_t)s * 4 + head] + e2; v2 = fmaxf(v2, 0.2f * v2);
        float w0 = __expf(v0), w1 = __expf(v1), w2 = __expf(v2);
        a0 += w0 * b2f(hp[0]);   d0 += w0;
        a1 += w1 * b2f(hp[128]); d1 += w1;
        a2 += w2 * b2f(hp[256]); d2 += w2;
    }
    size_t o = (size_t)n * COMBW;
    comb[o + t]       = f2b(a0 / fmaxf(d0, 1e-9f) + gb0[t]);
    comb[o + 128 + t] = f2b(a1 / fmaxf(d1, 1e-9f) + gb1[t]);
    comb[o + 256 + t] = f2b(a2 / fmaxf(d2, 1e-9f) + gb2[t]);
}

// ---------------- K5: out = relu(comb @ fcW^T + fcb), f32 out ----------------
// PB=1: fcW pre-packed bf16. PB=0: inline pack fallback.
template<int PB>
__global__ __launch_bounds__(256) void k_fc(const u16* __restrict__ comb,
                                            const float* __restrict__ fcW,
                                            const u16* __restrict__ pfcW,
                                            const float* __restrict__ fcb,
                                            float* __restrict__ out){
    int wave = threadIdx.x >> 6, lane = threadIdx.x & 63;
    int quad = lane >> 4, m = lane & 15;
    int row0 = blockIdx.x * 64 + wave * 16;
    int arow = row0 + m; if (arow >= NNODES) arow = NNODES - 1;
    const u16* ap = comb + (size_t)arow * COMBW + quad * 8;
    f32x4 c[8];
    #pragma unroll
    for (int f = 0; f < 8; f++) c[f] = (f32x4){0.f,0.f,0.f,0.f};
    for (int k = 0; k < COMBW; k += 32){
        bf16x8 a = *(const bf16x8*)(ap + k);
        #pragma unroll
        for (int f = 0; f < 8; f++){
            bf16x8 b;
            if (PB) b = *(const bf16x8*)(pfcW + (size_t)(f * 16 + m) * COMBW + k + quad * 8);
            else    b = pack8(fcW + (size_t)(f * 16 + m) * COMBW + k + quad * 8);
            c[f] = __builtin_amdgcn_mfma_f32_16x16x32_bf16(a, b, c[f], 0, 0, 0);
        }
    }
    #pragma unroll
    for (int f = 0; f < 8; f++){
        int colc = f * 16 + m;
        float bv = fcb[colc];
        #pragma unroll
        for (int i = 0; i < 4; i++){
            int r = row0 + quad * 4 + i;
            if (r < NNODES){
                float v = c[f][i] + bv; v = v > 0.f ? v : 0.f;
                out[(size_t)(2 * NB * HD) + (size_t)r * HD + colc] = v;
            }
        }
    }
}

extern "C" void kernel_launch(void* const* d_in, const int* in_sizes, int n_in,
                              void* d_out, int out_size, void* d_ws, size_t ws_size,
                              hipStream_t stream){
    const int* uid = (const int*)d_in[0];
    const int* iid = (const int*)d_in[1];
    const int* src = (const int*)d_in[2];
    const int* dst = (const int*)d_in[3];
    const float* fimg = (const float*)d_in[4];
    const float* ftxt = (const float*)d_in[5];
    const float* faud = (const float*)d_in[6];
    const float* utab = (const float*)d_in[7];
    const float* itab = (const float*)d_in[8];
    const float* Wi = (const float*)d_in[9],  *bi = (const float*)d_in[10];
    const float* Wt = (const float*)d_in[11], *bt = (const float*)d_in[12];
    const float* Wa = (const float*)d_in[13], *ba = (const float*)d_in[14];
    const float* gWi = (const float*)d_in[15], *ali = (const float*)d_in[16],
               *ari = (const float*)d_in[17], *gbi = (const float*)d_in[18];
    const float* gWt = (const float*)d_in[19], *alt = (const float*)d_in[20],
               *art = (const float*)d_in[21], *gbt = (const float*)d_in[22];
    const float* gWa = (const float*)d_in[23], *ala = (const float*)d_in[24],
               *ara = (const float*)d_in[25], *gba = (const float*)d_in[26];
    const float* fcW = (const float*)d_in[27], *fcb = (const float*)d_in[28];
    float* out = (float*)d_out;

    char* ws = (char*)d_ws;
    u16*   hcat = (u16*)  (ws + 0);           // 38.4 MB  [n][3][128] interleaved
    u16*   comb = (u16*)  (ws + 38400000);    // 38.4 MB
    float* x    = (float*)(ws + 76800000);    // 6.4 MB (reused per modality)
    float* el   = (float*)(ws + 83200000);    // 3 x 800000 B
    float* er   = (float*)(ws + 85600000);    // 3 x 800000 B
    int*   cnt  = (int*)  (ws + 88000000);    // 200 KB
    int*   fill = (int*)  (ws + 88200000);    // 200 KB
    int*   rp   = (int*)  (ws + 88400000);    // 200 KB (+pad)
    int*   col  = (int*)  (ws + 88600064);    // 6.4 MB
    float* w    = (float*)(ws + 95000064);    // 76.8 MB (edge weights, CSR order, optional)
    const size_t NEED_W = 95000064u + (size_t)NEDGES * 12 * sizeof(float);
    int*   bsum = (int*)x;                    // overlay: x first written after scans
    // Packed-weight overlays (zero extra ws):
    u16*   pW   = comb;                       // Wi|Wt|Wa bf16, dead before k_gat writes comb
    u16*   pWt_ = pW + 32768;
    u16*   pWa_ = pW + 57344;
    u16*   pfcW = (u16*)w;                    // packed after k_gat (w dead), before k_fc

    float* el0 = el,           *el1 = el + 200000, *el2 = el + 400000;
    float* er0 = er,           *er1 = er + 200000, *er2 = er + 400000;

    hipMemsetAsync(cnt, 0, 400000, stream);   // cnt + fill (adjacent)

    // CSR histogram + multi-block scan (scatter deferred until el/er ready)
    k_hist<<<(NEDGES + 255) / 256, 256, 0, stream>>>(dst, cnt);
    k_scan1<<<SCAN_BLOCKS, 256, 0, stream>>>(cnt, rp, bsum);
    k_scan2<<<1, 256, 0, stream>>>(bsum, rp);
    k_scan3<<<SCAN_BLOCKS, 256, 0, stream>>>(rp, bsum);

    // Pre-pack modality weights (into comb region — dead until k_gat)
    k_pack3<<<30, 256, 0, stream>>>(Wi, Wt, Wa, pW);

    // Embedding gathers straight to d_out
    k_gather<<<(2 * NB * HD / 8 + 255) / 256, 256, 0, stream>>>(uid, iid, utab, itab, out);

    // Modality pipelines (x buffer reused; stream-ordered)
    dim3 ngrid((NNODES + 255) / 256, 4);
    k_feat<<<(NNODES + 63) / 64, 256, 0, stream>>>(fimg, 1024, pW,   bi, x);
    k_node<<<ngrid, 256, 0, stream>>>(x, gWi, ali, ari, hcat,       el0, er0);
    k_feat<<<(NNODES + 63) / 64, 256, 0, stream>>>(ftxt, 768, pWt_, bt, x);
    k_node<<<ngrid, 256, 0, stream>>>(x, gWt, alt, art, hcat + 128, el1, er1);
    k_feat<<<(NNODES + 63) / 64, 256, 0, stream>>>(faud, 128, pWa_, ba, x);
    k_node<<<ngrid, 256, 0, stream>>>(x, gWa, ala, ara, hcat + 256, el2, er2);

    // Fused edge-softmax + aggregation for all 3 modalities
    if (ws_size >= NEED_W){
        k_scatter<1><<<(NEDGES + 255) / 256, 256, 0, stream>>>(src, dst, rp, fill, col,
                                                               el0, er0, el1, er1, el2, er2, w);
        k_gat<<<NNODES, 128, 0, stream>>>(rp, col, hcat, w, gbi, gbt, gba, comb);
        // Pre-pack fcW into (now dead) w region, then fc
        k_pack<<<24, 256, 0, stream>>>(fcW, pfcW, 6144);
        k_fc<1><<<(NNODES + 63) / 64, 256, 0, stream>>>(comb, fcW, pfcW, fcb, out);
    } else {
        k_scatter<0><<<(NEDGES + 255) / 256, 256, 0, stream>>>(src, dst, rp, fill, col,
                                                               el0, er0, el1, er1, el2, er2, w);
        k_gat_fb<<<NNODES, 128, 0, stream>>>(rp, col, hcat,
                                             el0, er0, el1, er1, el2, er2,
                                             gbi, gbt, gba, comb);
        k_fc<0><<<(NNODES + 63) / 64, 256, 0, stream>>>(comb, fcW, pfcW, fcb, out);
    }
}